// Round 5
// baseline (149.003 us; speedup 1.0000x reference)
//
#include <hip/hip_runtime.h>
#include <hip/hip_cooperative_groups.h>
#include <math.h>

namespace cg = cooperative_groups;

#define SRATE   32000
#define NFFT    1024
#define HOP     320
#define NBINS   513
#define NMELS   128
#define NFRAMES 1001
#define NB      16
#define TLEN    320000
#define PCEN_EPS 1e-6f
#define LN_EPS   1e-6f
#define MAXW     64   // max nonzero band width per mel column (measured ~27)

// ---- parallel-scan decomposition of the PCEN EMA ----
#define CL      16                    // chunk length (timesteps)
#define NCHUNK  63                    // ceil(1001/16)

// LDS pad for interleaved-complex float2 arrays: 1 extra complex per 8.
// Verified: every radix-4 stage's read (stride-256) and write (o=4n+k+p*mm)
// pattern is <=2-way bank aliasing under this map (2-way is free on CDNA4).
__device__ __forceinline__ int P(int i) { return i + (i >> 3); }
#define ZPAD 1152   // P(1023) = 1150

// ---------------------------------------------------------------------------
// Parallel prep: one block per mel packs the filterbank band; 5 extra blocks
// build the window and float2 twiddle tables.
__global__ __launch_bounds__(256) void k_prep(
    const float* __restrict__ fb, int* __restrict__ kmin, int* __restrict__ klen,
    float* __restrict__ wv, float* __restrict__ win, float2* __restrict__ twg)
{
    const int blk = blockIdx.x;
    const int tid = threadIdx.x;
    if (blk < NMELS) {
        const int m = blk;
        __shared__ int smin[4], smax[4];
        int lmin = 1 << 30, lmax = -1;
        for (int k = tid; k < NBINS; k += 256) {
            if (fb[k * NMELS + m] > 0.f) {
                if (k < lmin) lmin = k;
                if (k > lmax) lmax = k;
            }
        }
        #pragma unroll
        for (int off = 32; off; off >>= 1) {
            int om = __shfl_xor(lmin, off); if (om < lmin) lmin = om;
            int ox = __shfl_xor(lmax, off); if (ox > lmax) lmax = ox;
        }
        if ((tid & 63) == 0) { smin[tid >> 6] = lmin; smax[tid >> 6] = lmax; }
        __syncthreads();
        int k0 = min(min(smin[0], smin[1]), min(smin[2], smin[3]));
        int k1 = max(max(smax[0], smax[1]), max(smax[2], smax[3]));
        int L  = (k1 < 0) ? 0 : min(k1 - k0 + 1, MAXW);
        if (tid == 0) { kmin[m] = (k1 < 0) ? 0 : k0; klen[m] = L; }
        if (tid < L) wv[m * MAXW + tid] = fb[(k0 + tid) * NMELS + m];
    } else {
        const int i = (blk - NMELS) * 256 + tid;   // 0..1279
        if (i < NFFT) {
            float sp = sinpif((float)i * (1.0f / (float)NFFT));
            win[i] = sp * sp;
        } else if (i < NFFT + 256) {
            int n = i - NFFT;
            float sn, cn;
            sincospif((float)n * (1.0f / 512.0f), &sn, &cn);
            twg[n] = make_float2(cn, -sn);
        }
    }
}

// ---------------------------------------------------------------------------
// One block = TWO frames (two-for-one real FFT). Radix-4 Stockham, 5 stages,
// interleaved-complex float2 LDS with pad P(), b64 LDS traffic throughout.
__global__ __launch_bounds__(256) void k_melspec(
    const float* __restrict__ x,
    const int*   __restrict__ kmin,
    const int*   __restrict__ klen,
    const float* __restrict__ wv,
    const float* __restrict__ fb,     // dense fallback
    const float* __restrict__ win_g,
    const float2* __restrict__ twg,
    float* __restrict__ E,
    int usePacked)
{
    __shared__ float2 zA[ZPAD], zB[ZPAD];
    __shared__ float2 tws[256];

    const int tid = threadIdx.x;
    const int g   = blockIdx.x;          // frame pair: f0 = 2g, f1 = 2g+1
    const int f0  = 2 * g, f1 = 2 * g + 1;
    const int b0  = f0 / NFRAMES, t0f = f0 - b0 * NFRAMES;
    const int b1  = f1 / NFRAMES, t1f = f1 - b1 * NFRAMES;
    const float* xb0 = x + (size_t)b0 * TLEN;
    const float* xb1 = x + (size_t)b1 * TLEN;

    if (usePacked) {
        tws[tid] = twg[tid];
    } else {
        float sn, cn;
        sincospif((float)tid * (1.0f / 512.0f), &sn, &cn);
        tws[tid] = make_float2(cn, -sn);
    }

    // load with reflect padding + Hann window; interior frames take the
    // float4 fast path (base = 320t-512 is 0 mod 4, so 16B-aligned)
    const int base0 = t0f * HOP - (NFFT / 2);
    const int base1 = t1f * HOP - (NFFT / 2);
    const int i0 = tid * 4;
    const bool safe = usePacked &&
                      base0 >= 0 && base1 >= 0 &&
                      (base0 + NFFT - 1 < TLEN) && (base1 + NFFT - 1 < TLEN);
    if (safe) {
        float4 v0 = *(const float4*)(xb0 + base0 + i0);
        float4 v1 = *(const float4*)(xb1 + base1 + i0);
        float4 w  = *(const float4*)(win_g + i0);
        zA[P(i0 + 0)] = make_float2(v0.x * w.x, v1.x * w.x);
        zA[P(i0 + 1)] = make_float2(v0.y * w.y, v1.y * w.y);
        zA[P(i0 + 2)] = make_float2(v0.z * w.z, v1.z * w.z);
        zA[P(i0 + 3)] = make_float2(v0.w * w.w, v1.w * w.w);
    } else {
        #pragma unroll
        for (int u = 0; u < 4; ++u) {
            const int i = i0 + u;
            int j0 = base0 + i;
            j0 = (j0 < 0) ? -j0 : ((j0 >= TLEN) ? (2 * TLEN - 2 - j0) : j0);
            int j1 = base1 + i;
            j1 = (j1 < 0) ? -j1 : ((j1 >= TLEN) ? (2 * TLEN - 2 - j1) : j1);
            float w;
            if (usePacked) w = win_g[i];
            else { float sp = sinpif((float)i * (1.0f / (float)NFFT)); w = sp * sp; }
            zA[P(i)] = make_float2(xb0[j0] * w, xb1[j1] * w);
        }
    }
    __syncthreads();

    float2 *zs = zA, *zd = zB;
    #pragma unroll
    for (int st = 0; st < 5; ++st) {
        const int mm = 1 << (2 * st);
        const int n  = tid & ~(mm - 1);             // twiddle exponent j*m
        const int o  = (n << 2) | (tid & (mm - 1)); // k + 4*j*m
        float2 a0 = zs[P(tid)];
        float2 a1 = zs[P(tid + 256)];
        float2 a2 = zs[P(tid + 512)];
        float2 a3 = zs[P(tid + 768)];
        float2 w1 = tws[n];
        float c1 = w1.x, s1 = w1.y;
        float c2 = c1 * c1 - s1 * s1, s2 = 2.f * c1 * s1;
        float c3 = c1 * c2 - s1 * s2, s3 = c1 * s2 + s1 * c2;
        float t0r = a0.x + a2.x, t0i = a0.y + a2.y;
        float t1r = a0.x - a2.x, t1i = a0.y - a2.y;
        float t2r = a1.x + a3.x, t2i = a1.y + a3.y;
        float t3r = a1.y - a3.y, t3i = a3.x - a1.x;   // -i*(a1-a3)
        float y1r = t1r + t3r, y1i = t1i + t3i;
        float y2r = t0r - t2r, y2i = t0i - t2i;
        float y3r = t1r - t3r, y3i = t1i - t3i;
        zd[P(o)]          = make_float2(t0r + t2r,            t0i + t2i);
        zd[P(o + mm)]     = make_float2(y1r * c1 - y1i * s1,  y1r * s1 + y1i * c1);
        zd[P(o + 2 * mm)] = make_float2(y2r * c2 - y2i * s2,  y2r * s2 + y2i * c2);
        zd[P(o + 3 * mm)] = make_float2(y3r * c3 - y3i * s3,  y3r * s3 + y3i * c3);
        __syncthreads();
        float2* tp = zs; zs = zd; zd = tp;
    }
    // result in zs; zd is scratch

    // Untangle two-for-one: Z[k]=A+iB, Z[N-k]=C+iD -> pw[k] = (power0, power1)
    for (int k = tid; k < NBINS; k += 256) {
        float2 Z  = zs[P(k)];
        const int kr = (NFFT - k) & (NFFT - 1);
        float2 Zr = zs[P(kr)];
        float x1r = Z.x + Zr.x, x1i = Z.y - Zr.y;
        float x2r = Z.y + Zr.y, x2i = Zr.x - Z.x;
        zd[P(k)] = make_float2(0.25f * (x1r * x1r + x1i * x1i),
                               0.25f * (x2r * x2r + x2i * x2i));
    }
    __syncthreads();

    // mel projection: 128 threads, each does BOTH frames from the float2 pair
    if (tid < NMELS) {
        const int m = tid;
        float acc0 = 0.f, acc1 = 0.f;
        if (usePacked) {
            const int k0 = kmin[m], L = klen[m];
            const float* w = wv + m * MAXW;
            for (int j = 0; j < L; ++j) {
                float2 pk = zd[P(k0 + j)];
                float ww = w[j];
                acc0 += pk.x * ww; acc1 += pk.y * ww;
            }
        } else {
            for (int k = 0; k < NBINS; ++k) {
                float2 pk = zd[P(k)];
                float ww = fb[k * NMELS + m];
                acc0 += pk.x * ww; acc1 += pk.y * ww;
            }
        }
        E[(size_t)f0 * NMELS + m] = acc0;
        E[(size_t)f1 * NMELS + m] = acc1;
    }
}

// ---------------------------------------------------------------------------
// Fused PCEN (chunk-sum -> grid sync -> self-scan -> replay-from-LDS -> LN).
// Cooperative launch, 512 blocks = (b, chunk-pair). E is read ONCE.
__global__ __launch_bounds__(256) void k_pcen_fused(
    float* __restrict__ E, float* __restrict__ Bws,
    const float* __restrict__ p_ls, const float* __restrict__ p_la,
    const float* __restrict__ p_ld, const float* __restrict__ p_lr)
{
    __shared__ float sm[2 * CL][NMELS];   // 16 KB tile: 32 frames x 128 mels

    const int tid  = threadIdx.x;
    const int half = tid >> 7;
    const int m    = tid & 127;
    const int b    = blockIdx.x >> 5;     // 32 chunk-pairs per batch
    const int cp   = blockIdx.x & 31;
    const int c    = cp * 2 + half;

    const float s = expf(p_ls[0]);
    const float a = 1.f - s;

    // ---- phase 1: tile load + per-chunk affine sums ----
    const int F0  = cp * 2 * CL;
    const int nfr = min(2 * CL, NFRAMES - F0);
    {
        const float4* src = (const float4*)(E + ((size_t)b * NFRAMES + F0) * NMELS);
        float4* dst = (float4*)sm;
        for (int v = tid; v < nfr * (NMELS / 4); v += 256) dst[v] = src[v];
    }
    const float e0 = E[(size_t)b * NFRAMES * NMELS + m];   // EMA init, pre-sync
    __syncthreads();

    const int L = (c < NCHUNK) ? min(CL, NFRAMES - c * CL) : 0;
    float Bacc = 0.f;
    for (int j = 0; j < L; ++j)
        Bacc = a * Bacc + s * sm[half * CL + j][m];
    if (c < NCHUNK)
        Bws[((size_t)b * NCHUNK + c) * NMELS + m] = Bacc;

    __threadfence();
    cg::this_grid().sync();

    // ---- phase 2: self-scan prefix, replay from LDS, PCEN in place ----
    const float alpha = expf(p_la[0]);
    const float delta = expf(p_ld[0]);
    const float r     = expf(p_lr[0]);
    const float dr    = __powf(delta, r);
    const float a2 = a * a, a4 = a2 * a2, a8 = a4 * a4;
    const float a16 = a8 * a8;            // a^CL (all scanned chunks full)

    if (c < NCHUNK) {
        float M = e0;
        const float* Bcol = Bws + (size_t)b * NCHUNK * NMELS + m;
        for (int cc = 0; cc < c; ++cc)
            M = a16 * M + Bcol[(size_t)cc * NMELS];
        for (int j = 0; j < L; ++j) {
            float e = sm[half * CL + j][m];
            M = a * M + s * e;
            float den = __powf(PCEN_EPS + M, alpha);
            sm[half * CL + j][m] = __powf(e / den + delta, r) - dr;
        }
    }
    __syncthreads();

    // ---- LN over mel axis: 4 waves cover the 32 staged frames ----
    const int wid  = tid >> 6;
    const int lane = tid & 63;
    for (int row = wid; row < 2 * CL; row += 4) {
        if (F0 + row >= NFRAMES) break;
        float v0 = sm[row][lane], v1 = sm[row][lane + 64];
        float sum = v0 + v1;
        float sq  = v0 * v0 + v1 * v1;
        #pragma unroll
        for (int off = 32; off; off >>= 1) {
            sum += __shfl_xor(sum, off);
            sq  += __shfl_xor(sq,  off);
        }
        float mu  = sum * (1.f / 128.f);
        float var = sq * (1.f / 128.f) - mu * mu;
        float inv = rsqrtf(var + LN_EPS);
        float* p = E + ((size_t)b * NFRAMES + F0 + row) * NMELS;
        p[lane]      = (v0 - mu) * inv;
        p[lane + 64] = (v1 - mu) * inv;
    }
}

// ---------------------------------------------------------------------------
// Fallback serial PCEN + LN (used only if workspace is too small).
__global__ __launch_bounds__(256) void k_pcen_serial(
    float* __restrict__ E,
    const float* __restrict__ p_ls, const float* __restrict__ p_la,
    const float* __restrict__ p_ld, const float* __restrict__ p_lr)
{
    const int gid = blockIdx.x * blockDim.x + threadIdx.x;
    const int b = gid >> 7;
    const int m = gid & 127;

    const float s     = expf(p_ls[0]);
    const float alpha = expf(p_la[0]);
    const float delta = expf(p_ld[0]);
    const float r     = expf(p_lr[0]);
    const float dr    = powf(delta, r);
    const float a     = 1.f - s;

    float* col = E + (size_t)b * NFRAMES * NMELS + m;
    float M = col[0];
    for (int t = 0; t < NFRAMES; ++t) {
        float e = col[(size_t)t * NMELS];
        M = a * M + s * e;
        float den = __powf(PCEN_EPS + M, alpha);
        float p   = __powf(e / den + delta, r) - dr;
        col[(size_t)t * NMELS] = p;
    }
}

__global__ __launch_bounds__(256) void k_ln(float* __restrict__ out) {
    const int wid  = threadIdx.x >> 6;
    const int lane = threadIdx.x & 63;
    const int row  = blockIdx.x * 4 + wid;
    float* p = out + (size_t)row * NMELS;
    float v0 = p[lane], v1 = p[lane + 64];
    float sum = v0 + v1;
    float sq  = v0 * v0 + v1 * v1;
    #pragma unroll
    for (int off = 32; off; off >>= 1) {
        sum += __shfl_xor(sum, off);
        sq  += __shfl_xor(sq,  off);
    }
    float mu  = sum * (1.f / 128.f);
    float var = sq * (1.f / 128.f) - mu * mu;
    float inv = rsqrtf(var + LN_EPS);
    p[lane]      = (v0 - mu) * inv;
    p[lane + 64] = (v1 - mu) * inv;
}

// ---------------------------------------------------------------------------
extern "C" void kernel_launch(void* const* d_in, const int* in_sizes, int n_in,
                              void* d_out, int out_size, void* d_ws, size_t ws_size,
                              hipStream_t stream) {
    const float* x   = (const float*)d_in[0];
    const float* fb  = (const float*)d_in[1];
    const float* lsp = (const float*)d_in[2];
    const float* lap = (const float*)d_in[3];
    const float* ldp = (const float*)d_in[4];
    const float* lrp = (const float*)d_in[5];
    float* out = (float*)d_out;

    // ws layout (floats): kmin[128] klen[128] wv[8192] win[1024] tw[512] Bws[129024]
    const size_t packElems = 128 + 128 + 8192 + 1024 + 512;
    const size_t scanElems = (size_t)NB * NCHUNK * NMELS;   // 129024
    const size_t needPack  = packElems * 4;                 // ~40 KB
    const size_t needScan  = (packElems + scanElems) * 4;   // ~556 KB

    int usePacked = (ws_size >= needPack) ? 1 : 0;
    int useScan   = (ws_size >= needScan) ? 1 : 0;

    int*    kmin = (int*)d_ws;
    int*    klen = kmin + NMELS;
    float*  wv   = (float*)(klen + NMELS);
    float*  win  = wv + (size_t)NMELS * MAXW;
    float2* twg  = (float2*)(win + NFFT);
    float*  Bws  = (float*)(twg + 256);

    if (usePacked)
        k_prep<<<NMELS + 5, 256, 0, stream>>>(fb, kmin, klen, wv, win, twg);

    k_melspec<<<NB * NFRAMES / 2, 256, 0, stream>>>(
        x, kmin, klen, wv, fb, win, twg, out, usePacked);

    if (useScan) {
        void* args[] = { (void*)&out, (void*)&Bws, (void*)&lsp, (void*)&lap,
                         (void*)&ldp, (void*)&lrp };
        hipLaunchCooperativeKernel((const void*)k_pcen_fused,
                                   dim3(NB * 32), dim3(256), args, 0, stream);
    } else {
        k_pcen_serial<<<(NB * NMELS) / 256, 256, 0, stream>>>(out, lsp, lap, ldp, lrp);
        k_ln<<<(NB * NFRAMES) / 4, 256, 0, stream>>>(out);
    }
}

// Round 6
// 75.804 us; speedup vs baseline: 1.9656x; 1.9656x over previous
//
#include <hip/hip_runtime.h>
#include <math.h>

#define SRATE   32000
#define NFFT    1024
#define HOP     320
#define NBINS   513
#define NMELS   128
#define NFRAMES 1001
#define NB      16
#define TLEN    320000
#define PCEN_EPS 1e-6f
#define LN_EPS   1e-6f
#define MAXW     64   // max nonzero band width per mel column (measured ~27)

// ---- parallel-scan decomposition of the PCEN EMA ----
#define CL      16                    // chunk length (timesteps)
#define NCHUNK  63                    // ceil(1001/16)

// LDS pad for interleaved-complex float2 arrays: 1 extra complex per 8.
// Every radix-4 stage's read (stride-256) and write (o=4n+k+p*mm) pattern is
// <=2-way bank aliasing under this map (2-way is free on CDNA4).
__device__ __forceinline__ int P(int i) { return i + (i >> 3); }
#define ZPAD 1152   // P(1023) = 1150

// ---------------------------------------------------------------------------
// Parallel prep: one block per mel packs the filterbank band; 5 extra blocks
// build the window and float2 twiddle tables.
__global__ __launch_bounds__(256) void k_prep(
    const float* __restrict__ fb, int* __restrict__ kmin, int* __restrict__ klen,
    float* __restrict__ wv, float* __restrict__ win, float2* __restrict__ twg)
{
    const int blk = blockIdx.x;
    const int tid = threadIdx.x;
    if (blk < NMELS) {
        const int m = blk;
        __shared__ int smin[4], smax[4];
        int lmin = 1 << 30, lmax = -1;
        for (int k = tid; k < NBINS; k += 256) {
            if (fb[k * NMELS + m] > 0.f) {
                if (k < lmin) lmin = k;
                if (k > lmax) lmax = k;
            }
        }
        #pragma unroll
        for (int off = 32; off; off >>= 1) {
            int om = __shfl_xor(lmin, off); if (om < lmin) lmin = om;
            int ox = __shfl_xor(lmax, off); if (ox > lmax) lmax = ox;
        }
        if ((tid & 63) == 0) { smin[tid >> 6] = lmin; smax[tid >> 6] = lmax; }
        __syncthreads();
        int k0 = min(min(smin[0], smin[1]), min(smin[2], smin[3]));
        int k1 = max(max(smax[0], smax[1]), max(smax[2], smax[3]));
        int L  = (k1 < 0) ? 0 : min(k1 - k0 + 1, MAXW);
        if (tid == 0) { kmin[m] = (k1 < 0) ? 0 : k0; klen[m] = L; }
        if (tid < L) wv[m * MAXW + tid] = fb[(k0 + tid) * NMELS + m];
    } else {
        const int i = (blk - NMELS) * 256 + tid;   // 0..1279
        if (i < NFFT) {
            float sp = sinpif((float)i * (1.0f / (float)NFFT));
            win[i] = sp * sp;
        } else if (i < NFFT + 256) {
            int n = i - NFFT;
            float sn, cn;
            sincospif((float)n * (1.0f / 512.0f), &sn, &cn);
            twg[n] = make_float2(cn, -sn);
        }
    }
}

// ---------------------------------------------------------------------------
// One block = TWO frames (two-for-one real FFT). Radix-4 Stockham, 5 stages,
// interleaved-complex float2 LDS with pad P(), b64 LDS traffic throughout.
__global__ __launch_bounds__(256) void k_melspec(
    const float* __restrict__ x,
    const int*   __restrict__ kmin,
    const int*   __restrict__ klen,
    const float* __restrict__ wv,
    const float* __restrict__ fb,     // dense fallback
    const float* __restrict__ win_g,
    const float2* __restrict__ twg,
    float* __restrict__ E,
    int usePacked)
{
    __shared__ float2 zA[ZPAD], zB[ZPAD];
    __shared__ float2 tws[256];

    const int tid = threadIdx.x;
    const int g   = blockIdx.x;          // frame pair: f0 = 2g, f1 = 2g+1
    const int f0  = 2 * g, f1 = 2 * g + 1;
    const int b0  = f0 / NFRAMES, t0f = f0 - b0 * NFRAMES;
    const int b1  = f1 / NFRAMES, t1f = f1 - b1 * NFRAMES;
    const float* xb0 = x + (size_t)b0 * TLEN;
    const float* xb1 = x + (size_t)b1 * TLEN;

    if (usePacked) {
        tws[tid] = twg[tid];
    } else {
        float sn, cn;
        sincospif((float)tid * (1.0f / 512.0f), &sn, &cn);
        tws[tid] = make_float2(cn, -sn);
    }

    // load with reflect padding + Hann window; interior frames take the
    // float4 fast path (base = 320t-512 is 0 mod 4, so 16B-aligned)
    const int base0 = t0f * HOP - (NFFT / 2);
    const int base1 = t1f * HOP - (NFFT / 2);
    const int i0 = tid * 4;
    const bool safe = usePacked &&
                      base0 >= 0 && base1 >= 0 &&
                      (base0 + NFFT - 1 < TLEN) && (base1 + NFFT - 1 < TLEN);
    if (safe) {
        float4 v0 = *(const float4*)(xb0 + base0 + i0);
        float4 v1 = *(const float4*)(xb1 + base1 + i0);
        float4 w  = *(const float4*)(win_g + i0);
        zA[P(i0 + 0)] = make_float2(v0.x * w.x, v1.x * w.x);
        zA[P(i0 + 1)] = make_float2(v0.y * w.y, v1.y * w.y);
        zA[P(i0 + 2)] = make_float2(v0.z * w.z, v1.z * w.z);
        zA[P(i0 + 3)] = make_float2(v0.w * w.w, v1.w * w.w);
    } else {
        #pragma unroll
        for (int u = 0; u < 4; ++u) {
            const int i = i0 + u;
            int j0 = base0 + i;
            j0 = (j0 < 0) ? -j0 : ((j0 >= TLEN) ? (2 * TLEN - 2 - j0) : j0);
            int j1 = base1 + i;
            j1 = (j1 < 0) ? -j1 : ((j1 >= TLEN) ? (2 * TLEN - 2 - j1) : j1);
            float w;
            if (usePacked) w = win_g[i];
            else { float sp = sinpif((float)i * (1.0f / (float)NFFT)); w = sp * sp; }
            zA[P(i)] = make_float2(xb0[j0] * w, xb1[j1] * w);
        }
    }
    __syncthreads();

    float2 *zs = zA, *zd = zB;
    #pragma unroll
    for (int st = 0; st < 5; ++st) {
        const int mm = 1 << (2 * st);
        const int n  = tid & ~(mm - 1);             // twiddle exponent j*m
        const int o  = (n << 2) | (tid & (mm - 1)); // k + 4*j*m
        float2 a0 = zs[P(tid)];
        float2 a1 = zs[P(tid + 256)];
        float2 a2 = zs[P(tid + 512)];
        float2 a3 = zs[P(tid + 768)];
        float2 w1 = tws[n];
        float c1 = w1.x, s1 = w1.y;
        float c2 = c1 * c1 - s1 * s1, s2 = 2.f * c1 * s1;
        float c3 = c1 * c2 - s1 * s2, s3 = c1 * s2 + s1 * c2;
        float t0r = a0.x + a2.x, t0i = a0.y + a2.y;
        float t1r = a0.x - a2.x, t1i = a0.y - a2.y;
        float t2r = a1.x + a3.x, t2i = a1.y + a3.y;
        float t3r = a1.y - a3.y, t3i = a3.x - a1.x;   // -i*(a1-a3)
        float y1r = t1r + t3r, y1i = t1i + t3i;
        float y2r = t0r - t2r, y2i = t0i - t2i;
        float y3r = t1r - t3r, y3i = t1i - t3i;
        zd[P(o)]          = make_float2(t0r + t2r,            t0i + t2i);
        zd[P(o + mm)]     = make_float2(y1r * c1 - y1i * s1,  y1r * s1 + y1i * c1);
        zd[P(o + 2 * mm)] = make_float2(y2r * c2 - y2i * s2,  y2r * s2 + y2i * c2);
        zd[P(o + 3 * mm)] = make_float2(y3r * c3 - y3i * s3,  y3r * s3 + y3i * c3);
        __syncthreads();
        float2* tp = zs; zs = zd; zd = tp;
    }
    // result in zs; zd is scratch

    // Untangle two-for-one: Z[k]=A+iB, Z[N-k]=C+iD -> pw[k] = (power0, power1)
    for (int k = tid; k < NBINS; k += 256) {
        float2 Z  = zs[P(k)];
        const int kr = (NFFT - k) & (NFFT - 1);
        float2 Zr = zs[P(kr)];
        float x1r = Z.x + Zr.x, x1i = Z.y - Zr.y;
        float x2r = Z.y + Zr.y, x2i = Zr.x - Z.x;
        zd[P(k)] = make_float2(0.25f * (x1r * x1r + x1i * x1i),
                               0.25f * (x2r * x2r + x2i * x2i));
    }
    __syncthreads();

    // mel projection: 128 threads, each does BOTH frames from the float2 pair
    if (tid < NMELS) {
        const int m = tid;
        float acc0 = 0.f, acc1 = 0.f;
        if (usePacked) {
            const int k0 = kmin[m], L = klen[m];
            const float* w = wv + m * MAXW;
            for (int j = 0; j < L; ++j) {
                float2 pk = zd[P(k0 + j)];
                float ww = w[j];
                acc0 += pk.x * ww; acc1 += pk.y * ww;
            }
        } else {
            for (int k = 0; k < NBINS; ++k) {
                float2 pk = zd[P(k)];
                float ww = fb[k * NMELS + m];
                acc0 += pk.x * ww; acc1 += pk.y * ww;
            }
        }
        E[(size_t)f0 * NMELS + m] = acc0;
        E[(size_t)f1 * NMELS + m] = acc1;
    }
}

// ---------------------------------------------------------------------------
// PCEN phase 1: per-(b,chunk,m) affine offset B_c = s * sum_j a^{L-1-j} e_j.
// Full chunks take an MLP-friendly path: 16 independent loads in flight, then
// 4 short FMA chains merged with a^4/a^8/a^12. Also snapshots E[:,0,:].
__global__ __launch_bounds__(256) void k_pcen_chunk(
    const float* __restrict__ E, float* __restrict__ Bws,
    float* __restrict__ E0ws, const float* __restrict__ p_ls)
{
    const int gid = blockIdx.x * blockDim.x + threadIdx.x;
    const int m = gid & (NMELS - 1);
    const int c = (gid >> 7) % NCHUNK;
    const int b = gid / (NMELS * NCHUNK);

    const float s = expf(p_ls[0]);
    const float a = 1.f - s;

    const int t0 = c * CL;
    const int L  = (t0 + CL <= NFRAMES) ? CL : (NFRAMES - t0);
    const float* col = E + (size_t)b * NFRAMES * NMELS + m;

    if (c == 0) E0ws[b * NMELS + m] = col[0];

    float Bacc;
    if (L == CL) {
        float e[CL];
        #pragma unroll
        for (int j = 0; j < CL; ++j)
            e[j] = col[(size_t)(t0 + j) * NMELS];
        float p0 = 0.f, p1 = 0.f, p2 = 0.f, p3 = 0.f;
        #pragma unroll
        for (int u = 0; u < 4; ++u) {
            p0 = a * p0 + s * e[u];
            p1 = a * p1 + s * e[4 + u];
            p2 = a * p2 + s * e[8 + u];
            p3 = a * p3 + s * e[12 + u];
        }
        const float a2 = a * a, a4 = a2 * a2, a8 = a4 * a4, a12 = a8 * a4;
        Bacc = a12 * p0 + a8 * p1 + a4 * p2 + p3;
    } else {
        Bacc = 0.f;
        for (int j = 0; j < L; ++j)
            Bacc = a * Bacc + s * col[(size_t)(t0 + j) * NMELS];
    }
    Bws[gid] = Bacc;
}

// ---------------------------------------------------------------------------
// PCEN phase 2 fused with layernorm. One block = (b, chunk-pair). Each half
// recomputes its chunk's EMA carry by scanning Bws (batched 8-wide loads),
// replays the chunk with pointwise PCEN into LDS, then 4 waves layernorm the
// 32 frames in place.
__global__ __launch_bounds__(256) void k_pcen_ln(
    float* __restrict__ E, const float* __restrict__ Bws,
    const float* __restrict__ E0ws,
    const float* __restrict__ p_ls, const float* __restrict__ p_la,
    const float* __restrict__ p_ld, const float* __restrict__ p_lr)
{
    __shared__ float sm[2 * CL][NMELS];   // 16 KB

    const int tid  = threadIdx.x;
    const int half = tid >> 7;
    const int m    = tid & 127;
    const int b    = blockIdx.x >> 5;     // 32 chunk-pairs per batch
    const int cp   = blockIdx.x & 31;
    const int c    = cp * 2 + half;

    const float s     = expf(p_ls[0]);
    const float alpha = expf(p_la[0]);
    const float delta = expf(p_ld[0]);
    const float r     = expf(p_lr[0]);
    const float dr    = __powf(delta, r);
    const float a     = 1.f - s;
    const float a2 = a * a, a4 = a2 * a2, a8 = a4 * a4;
    const float a16 = a8 * a8;            // a^CL (all scanned chunks full)

    if (c < NCHUNK) {
        // self-scan: carry entering chunk c, 8-wide batched loads for MLP
        float M = E0ws[b * NMELS + m];
        const float* Bcol = Bws + (size_t)b * NCHUNK * NMELS + m;
        int cc = 0;
        for (; cc + 8 <= c; cc += 8) {
            float b0 = Bcol[(size_t)(cc + 0) * NMELS];
            float b1 = Bcol[(size_t)(cc + 1) * NMELS];
            float b2 = Bcol[(size_t)(cc + 2) * NMELS];
            float b3 = Bcol[(size_t)(cc + 3) * NMELS];
            float b4 = Bcol[(size_t)(cc + 4) * NMELS];
            float b5 = Bcol[(size_t)(cc + 5) * NMELS];
            float b6 = Bcol[(size_t)(cc + 6) * NMELS];
            float b7 = Bcol[(size_t)(cc + 7) * NMELS];
            M = a16 * M + b0; M = a16 * M + b1; M = a16 * M + b2; M = a16 * M + b3;
            M = a16 * M + b4; M = a16 * M + b5; M = a16 * M + b6; M = a16 * M + b7;
        }
        for (; cc < c; ++cc)
            M = a16 * M + Bcol[(size_t)cc * NMELS];

        const int t0 = c * CL;
        const int L  = (t0 + CL <= NFRAMES) ? CL : (NFRAMES - t0);
        const float* col = E + ((size_t)b * NFRAMES + t0) * NMELS + m;
        for (int j = 0; j < L; ++j) {
            float e = col[(size_t)j * NMELS];
            M = a * M + s * e;
            float den = __powf(PCEN_EPS + M, alpha);
            sm[half * CL + j][m] = __powf(e / den + delta, r) - dr;
        }
    }
    __syncthreads();

    // layernorm: 4 waves cover the 32 staged frames
    const int wid  = tid >> 6;
    const int lane = tid & 63;
    for (int row = wid; row < 2 * CL; row += 4) {
        const int cc = cp * 2 + (row >> 4);
        if (cc >= NCHUNK) continue;
        const int j   = row & (CL - 1);
        const int tt0 = cc * CL;
        const int LL  = (tt0 + CL <= NFRAMES) ? CL : (NFRAMES - tt0);
        if (j >= LL) continue;
        float v0 = sm[row][lane], v1 = sm[row][lane + 64];
        float sum = v0 + v1;
        float sq  = v0 * v0 + v1 * v1;
        #pragma unroll
        for (int off = 32; off; off >>= 1) {
            sum += __shfl_xor(sum, off);
            sq  += __shfl_xor(sq,  off);
        }
        float mu  = sum * (1.f / 128.f);
        float var = sq * (1.f / 128.f) - mu * mu;
        float inv = rsqrtf(var + LN_EPS);
        float* p = E + ((size_t)b * NFRAMES + tt0 + j) * NMELS;
        p[lane]      = (v0 - mu) * inv;
        p[lane + 64] = (v1 - mu) * inv;
    }
}

// ---------------------------------------------------------------------------
// Fallback serial PCEN + LN (used only if workspace is too small).
__global__ __launch_bounds__(256) void k_pcen_serial(
    float* __restrict__ E,
    const float* __restrict__ p_ls, const float* __restrict__ p_la,
    const float* __restrict__ p_ld, const float* __restrict__ p_lr)
{
    const int gid = blockIdx.x * blockDim.x + threadIdx.x;
    const int b = gid >> 7;
    const int m = gid & 127;

    const float s     = expf(p_ls[0]);
    const float alpha = expf(p_la[0]);
    const float delta = expf(p_ld[0]);
    const float r     = expf(p_lr[0]);
    const float dr    = powf(delta, r);
    const float a     = 1.f - s;

    float* col = E + (size_t)b * NFRAMES * NMELS + m;
    float M = col[0];
    for (int t = 0; t < NFRAMES; ++t) {
        float e = col[(size_t)t * NMELS];
        M = a * M + s * e;
        float den = __powf(PCEN_EPS + M, alpha);
        float p   = __powf(e / den + delta, r) - dr;
        col[(size_t)t * NMELS] = p;
    }
}

__global__ __launch_bounds__(256) void k_ln(float* __restrict__ out) {
    const int wid  = threadIdx.x >> 6;
    const int lane = threadIdx.x & 63;
    const int row  = blockIdx.x * 4 + wid;
    float* p = out + (size_t)row * NMELS;
    float v0 = p[lane], v1 = p[lane + 64];
    float sum = v0 + v1;
    float sq  = v0 * v0 + v1 * v1;
    #pragma unroll
    for (int off = 32; off; off >>= 1) {
        sum += __shfl_xor(sum, off);
        sq  += __shfl_xor(sq,  off);
    }
    float mu  = sum * (1.f / 128.f);
    float var = sq * (1.f / 128.f) - mu * mu;
    float inv = rsqrtf(var + LN_EPS);
    p[lane]      = (v0 - mu) * inv;
    p[lane + 64] = (v1 - mu) * inv;
}

// ---------------------------------------------------------------------------
extern "C" void kernel_launch(void* const* d_in, const int* in_sizes, int n_in,
                              void* d_out, int out_size, void* d_ws, size_t ws_size,
                              hipStream_t stream) {
    const float* x   = (const float*)d_in[0];
    const float* fb  = (const float*)d_in[1];
    const float* lsp = (const float*)d_in[2];
    const float* lap = (const float*)d_in[3];
    const float* ldp = (const float*)d_in[4];
    const float* lrp = (const float*)d_in[5];
    float* out = (float*)d_out;

    // ws layout (floats): kmin[128] klen[128] wv[8192] win[1024] tw[512]
    //                     Bws[129024] E0ws[2048]
    const size_t packElems = 128 + 128 + 8192 + 1024 + 512;
    const size_t scanElems = (size_t)NB * NCHUNK * NMELS;   // 129024
    const size_t needPack  = packElems * 4;
    const size_t needScan  = (packElems + scanElems + (size_t)NB * NMELS) * 4;

    int usePacked = (ws_size >= needPack) ? 1 : 0;
    int useScan   = (ws_size >= needScan) ? 1 : 0;

    int*    kmin = (int*)d_ws;
    int*    klen = kmin + NMELS;
    float*  wv   = (float*)(klen + NMELS);
    float*  win  = wv + (size_t)NMELS * MAXW;
    float2* twg  = (float2*)(win + NFFT);
    float*  Bws  = (float*)(twg + 256);
    float*  E0ws = Bws + scanElems;

    if (usePacked)
        k_prep<<<NMELS + 5, 256, 0, stream>>>(fb, kmin, klen, wv, win, twg);

    k_melspec<<<NB * NFRAMES / 2, 256, 0, stream>>>(
        x, kmin, klen, wv, fb, win, twg, out, usePacked);

    if (useScan) {
        const int nThread = NB * NCHUNK * NMELS;                 // 129024
        k_pcen_chunk<<<nThread / 256, 256, 0, stream>>>(out, Bws, E0ws, lsp);
        k_pcen_ln<<<NB * 32, 256, 0, stream>>>(out, Bws, E0ws, lsp, lap, ldp, lrp);
    } else {
        k_pcen_serial<<<(NB * NMELS) / 256, 256, 0, stream>>>(out, lsp, lap, ldp, lrp);
        k_ln<<<(NB * NFRAMES) / 4, 256, 0, stream>>>(out);
    }
}